// Round 2
// baseline (1374.607 us; speedup 1.0000x reference)
//
#include <hip/hip_runtime.h>
#include <hip/hip_bf16.h>
#include <math.h>

#define T_DATA 100000
#define NGRP   24
#define ESYN   2000
#define ISYN   500
#define NTOT   2400000   // T_DATA * NGRP

// RNG scheme selector:
//   0 = JAX partitionable threefry, 32-bit fold = out1 ^ out2  [jax>=0.4.36 default]
//   1 = partitionable, keep out2
//   2 = partitionable, keep out1
//   3 = legacy split-iota threefry
#define RNG_SCHEME 0

__device__ __forceinline__ unsigned tf_rotl(unsigned x, int r) {
    return (x << r) | (x >> (32 - r));
}

__device__ __forceinline__ void threefry2x32(unsigned c0, unsigned c1,
                                             unsigned& o0, unsigned& o1) {
    const unsigned K0 = 0u, K1 = 42u;                 // jax.random.key(42) -> (0,42)
    const unsigned K2 = 0x1BD11BDAu ^ K0 ^ K1;
    unsigned x0 = c0 + K0;
    unsigned x1 = c1 + K1;
#define TFR(r) { x0 += x1; x1 = tf_rotl(x1, (r)); x1 ^= x0; }
    TFR(13) TFR(15) TFR(26) TFR(6)   x0 += K1; x1 += K2 + 1u;
    TFR(17) TFR(29) TFR(16) TFR(24)  x0 += K2; x1 += K0 + 2u;
    TFR(13) TFR(15) TFR(26) TFR(6)   x0 += K0; x1 += K1 + 3u;
    TFR(17) TFR(29) TFR(16) TFR(24)  x0 += K1; x1 += K2 + 4u;
    TFR(13) TFR(15) TFR(26) TFR(6)   x0 += K2; x1 += K0 + 5u;
#undef TFR
    o0 = x0; o1 = x1;
}

__device__ __forceinline__ unsigned rng_bits(unsigned i) {
#if RNG_SCHEME == 0
    unsigned a, b; threefry2x32(0u, i, a, b); return a ^ b;
#elif RNG_SCHEME == 1
    unsigned a, b; threefry2x32(0u, i, a, b); return b;
#elif RNG_SCHEME == 2
    unsigned a, b; threefry2x32(0u, i, a, b); return a;
#else
    const unsigned H = (unsigned)(NTOT / 2);
    unsigned a, b;
    if (i < H) { threefry2x32(i, i + H, a, b); return a; }
    else       { threefry2x32(i - H, i, a, b); return b; }
#endif
}

// ---------------------------------------------------------------------------
// Kernel 1: tiny prep — synapse->subunit index, FIR kernels, obs kernel
// ---------------------------------------------------------------------------
__global__ void prep_kernel(const float* __restrict__ C_e,
                            const float* __restrict__ C_i,
                            const float* __restrict__ W_syn,
                            const float* __restrict__ W_obs,
                            const float* __restrict__ cosb,   // [13][200]
                            const float* __restrict__ obsb,   // [29][401]
                            int* __restrict__ idx_e, int* __restrict__ idx_i,
                            float* __restrict__ ek, float* __restrict__ ik,
                            float* __restrict__ ok) {
    int i = blockIdx.x * blockDim.x + threadIdx.x;
    if (i < ESYN) {
        int r = -1;
        for (int g = 0; g < 25; ++g)
            if (C_e[g * ESYN + i] > 0.5f) { r = g - 1; break; }
        idx_e[i] = r;            // -1 => subunit 0 (dropped by C[1:])
    } else if (i < ESYN + ISYN) {
        int s = i - ESYN; int r = -1;
        for (int g = 0; g < 25; ++g)
            if (C_i[g * ISYN + s] > 0.5f) { r = g - 1; break; }
        idx_i[s] = r;
    } else if (i < ESYN + ISYN + NGRP * 200) {
        int q = i - (ESYN + ISYN);
        int g = q / 200, j = q % 200;
        float ae = 0.f, ai = 0.f;
        for (int b = 0; b < 13; ++b) {
            float we = W_syn[(g * 13 + b) * 2 + 0];
            float wi = W_syn[(g * 13 + b) * 2 + 1];
            float cb = cosb[b * 200 + j];
            ae = fmaf(we * we, cb, ae);
            ai = fmaf(wi * wi, cb, ai);
        }
        ek[g * 200 + j] = ae;
        ik[g * 200 + j] = -ai;   // i-kernel is negated in the reference
    } else if (i < ESYN + ISYN + NGRP * 200 + NGRP * 401) {
        int q = i - (ESYN + ISYN + NGRP * 200);
        int g = q / 401, tau = q % 401;
        float a = 0.f;
        for (int b = 0; b < 29; ++b)
            a = fmaf(W_obs[g * 29 + b], obsb[b * 401 + tau], a);
        ok[g * 401 + tau] = a;
    }
}

// ---------------------------------------------------------------------------
// Kernel 2: spike histogram — syn_e/syn_i [G][T]   (memory-bound, ~1 GB read)
// One wave per timestep, LDS counters, atomic only on (rare, 2%) spikes.
// ---------------------------------------------------------------------------
__global__ __launch_bounds__(256) void hist_kernel(
        const float* __restrict__ S_e, const float* __restrict__ S_i,
        const int* __restrict__ idx_e, const int* __restrict__ idx_i,
        float* __restrict__ synE, float* __restrict__ synI) {
    __shared__ float cntE[4][32];
    __shared__ float cntI[4][32];
    const int wv = threadIdx.x >> 6;
    const int lane = threadIdx.x & 63;
    const int t = blockIdx.x * 4 + wv;          // grid = 25000 blocks exactly
    if (lane < 32) { cntE[wv][lane] = 0.f; cntI[wv][lane] = 0.f; }
    __syncthreads();

    const float4* re = (const float4*)(S_e + (size_t)t * ESYN);
    for (int c = lane; c < ESYN / 4; c += 64) {
        float4 v = re[c];
        int cb = c * 4;
        if (v.x != 0.f) { int g = idx_e[cb + 0]; if (g >= 0) atomicAdd(&cntE[wv][g], v.x); }
        if (v.y != 0.f) { int g = idx_e[cb + 1]; if (g >= 0) atomicAdd(&cntE[wv][g], v.y); }
        if (v.z != 0.f) { int g = idx_e[cb + 2]; if (g >= 0) atomicAdd(&cntE[wv][g], v.z); }
        if (v.w != 0.f) { int g = idx_e[cb + 3]; if (g >= 0) atomicAdd(&cntE[wv][g], v.w); }
    }
    const float4* ri = (const float4*)(S_i + (size_t)t * ISYN);
    for (int c = lane; c < ISYN / 4; c += 64) {
        float4 v = ri[c];
        int cb = c * 4;
        if (v.x != 0.f) { int g = idx_i[cb + 0]; if (g >= 0) atomicAdd(&cntI[wv][g], v.x); }
        if (v.y != 0.f) { int g = idx_i[cb + 1]; if (g >= 0) atomicAdd(&cntI[wv][g], v.y); }
        if (v.z != 0.f) { int g = idx_i[cb + 2]; if (g >= 0) atomicAdd(&cntI[wv][g], v.z); }
        if (v.w != 0.f) { int g = idx_i[cb + 3]; if (g >= 0) atomicAdd(&cntI[wv][g], v.w); }
    }
    __syncthreads();
    if (lane < NGRP) {
        synE[(size_t)lane * T_DATA + t] = cntE[wv][lane];
        synI[(size_t)lane * T_DATA + t] = cntI[wv][lane];
    }
}

// ---------------------------------------------------------------------------
// Kernel 3: FIR filters + sigmoid + threefry bernoulli.
// Block = 128 threads, one subunit g, TT=1024 timesteps; 8 outputs/thread via
// a circular register window (1 new LDS read per tap instead of 8).
// ---------------------------------------------------------------------------
constexpr int TT = 1024;
constexpr int BLK3 = 128;

__global__ __launch_bounds__(128) void filter_kernel(
        const float* __restrict__ Z,
        const float* __restrict__ synE, const float* __restrict__ synI,
        const float* __restrict__ ek, const float* __restrict__ ik,
        const float* __restrict__ ok, const float* __restrict__ Theta,
        float* __restrict__ out) {
    __shared__ float2 syn_l[TT + 200];   // (e,i) packed -> ds_read_b64
    __shared__ float  z_l[TT + 400];
    __shared__ float2 kern_l[200];       // (ek, ik)
    __shared__ float  ok_l[401];

    const int g  = blockIdx.y;
    const int t0 = blockIdx.x * TT;
    const int tid = threadIdx.x;

    for (int p = tid; p < TT + 200; p += BLK3) {
        int t = t0 - 200 + p;
        float e = 0.f, ii = 0.f;
        if (t >= 0 && t < T_DATA) {
            e  = synE[(size_t)g * T_DATA + t];
            ii = synI[(size_t)g * T_DATA + t];
        }
        syn_l[p] = make_float2(e, ii);
    }
    for (int p = tid; p < TT + 400; p += BLK3) {
        int t = t0 - 200 + p;
        z_l[p] = (t >= 0 && t < T_DATA) ? Z[t] : 0.f;
    }
    for (int p = tid; p < 200; p += BLK3)
        kern_l[p] = make_float2(ek[g * 200 + p], ik[g * 200 + p]);
    for (int p = tid; p < 401; p += BLK3)
        ok_l[p] = ok[g * 401 + p];
    __syncthreads();

    float accS[8], accZ[8];
#pragma unroll
    for (int k = 0; k < 8; ++k) { accS[k] = 0.f; accZ[k] = 0.f; }

    // --- synaptic FIR: out[t] += sum_j syn[t-1-j]*kern[j], j in [0,200) ---
    {
        const int B = tid * 8 + 199;   // lds index for (k=0, j=0)
        float2 w[8];                   // slot s = (lds_idx - B) & 7
#pragma unroll
        for (int p = 0; p < 8; ++p) w[p] = syn_l[B + p];
        for (int nb = 0; nb < 200; nb += 8) {
#pragma unroll
            for (int jj = 0; jj < 8; ++jj) {
                const int n = nb + jj;
                const float2 kv = kern_l[n];
#pragma unroll
                for (int k = 0; k < 8; ++k) {
                    const float2 d = w[(k - jj) & 7];
                    accS[k] = fmaf(d.x, kv.x, fmaf(d.y, kv.y, accS[k]));
                }
                if (n < 199) w[(7 - jj) & 7] = syn_l[B - n - 1];
            }
        }
    }

    // --- obs FIR: out[t] += sum_n Z[t+200-n]*ok[n], n in [0,400] ---
    {
        const int Bz = tid * 8 + 400;
        float wz[8];
#pragma unroll
        for (int p = 0; p < 8; ++p) wz[p] = z_l[Bz + p];
        for (int nb = 0; nb < 400; nb += 8) {
#pragma unroll
            for (int jj = 0; jj < 8; ++jj) {
                const int n = nb + jj;
                const float kv = ok_l[n];
#pragma unroll
                for (int k = 0; k < 8; ++k)
                    accZ[k] = fmaf(wz[(k - jj) & 7], kv, accZ[k]);
                wz[(7 - jj) & 7] = z_l[Bz - n - 1];   // min = tid*8 >= 0
            }
        }
        const float kv = ok_l[400];    // epilogue tap; 400 % 8 == 0 -> slot k
#pragma unroll
        for (int k = 0; k < 8; ++k)
            accZ[k] = fmaf(wz[k], kv, accZ[k]);
    }

    const float theta_g = Theta[g];
#pragma unroll
    for (int k = 0; k < 8; ++k) {
        int t = t0 + tid * 8 + k;
        if (t < T_DATA) {
            double x  = (double)accS[k] + (double)accZ[k] + (double)theta_g;
            double Pd = 1.0 / (1.0 + exp(-x));
            float  Pf = (float)Pd;
            unsigned i = (unsigned)(t * NGRP + g);
            unsigned bits = rng_bits(i);
            float u = __uint_as_float((bits >> 9) | 0x3f800000u) - 1.0f;
            size_t o = (size_t)t * NGRP + g;
            out[o]        = (u < Pf) ? 1.0f : 0.0f;  // Z_out
            out[NTOT + o] = Pf;                      // P
        }
    }
}

extern "C" void kernel_launch(void* const* d_in, const int* in_sizes, int n_in,
                              void* d_out, int out_size, void* d_ws, size_t ws_size,
                              hipStream_t stream) {
    const float* Z     = (const float*)d_in[0];
    const float* S_e   = (const float*)d_in[1];
    const float* S_i   = (const float*)d_in[2];
    const float* C_e   = (const float*)d_in[3];
    const float* C_i   = (const float*)d_in[4];
    const float* W_syn = (const float*)d_in[5];
    const float* Theta = (const float*)d_in[6];
    const float* W_obs = (const float*)d_in[7];
    const float* cosb  = (const float*)d_in[8];
    const float* obsb  = (const float*)d_in[9];

    float* ws   = (float*)d_ws;
    float* synE = ws;                    // 2,400,000 f32
    float* synI = synE + NTOT;           // 2,400,000 f32
    float* ek   = synI + NTOT;           // 24*200
    float* ik   = ek + NGRP * 200;       // 24*200
    float* ok   = ik + NGRP * 200;       // 24*401
    int*   idx_e = (int*)(ok + NGRP * 401);  // 2000
    int*   idx_i = idx_e + ESYN;             // 500
    // total ~18.4 MiB of d_ws

    const int prep_items = ESYN + ISYN + NGRP * 200 + NGRP * 401;
    prep_kernel<<<(prep_items + 255) / 256, 256, 0, stream>>>(
        C_e, C_i, W_syn, W_obs, cosb, obsb, idx_e, idx_i, ek, ik, ok);

    hist_kernel<<<T_DATA / 4, 256, 0, stream>>>(S_e, S_i, idx_e, idx_i, synE, synI);

    dim3 grid3((T_DATA + TT - 1) / TT, NGRP);
    filter_kernel<<<grid3, BLK3, 0, stream>>>(Z, synE, synI, ek, ik, ok, Theta,
                                              (float*)d_out);
}

// Round 3
// 1268.639 us; speedup vs baseline: 1.0835x; 1.0835x over previous
//
#include <hip/hip_runtime.h>
#include <hip/hip_bf16.h>
#include <math.h>

#define T_DATA 100000
#define NGRP   24
#define ESYN   2000
#define ISYN   500
#define NTOT   2400000   // T_DATA * NGRP

// JAX partitionable threefry, 32-bit fold = out1 ^ out2 (verified R2)
__device__ __forceinline__ unsigned tf_rotl(unsigned x, int r) {
    return (x << r) | (x >> (32 - r));
}

__device__ __forceinline__ unsigned rng_bits(unsigned i) {
    const unsigned K0 = 0u, K1 = 42u;                 // jax.random.key(42)
    const unsigned K2 = 0x1BD11BDAu ^ K0 ^ K1;
    unsigned x0 = 0u + K0;
    unsigned x1 = i  + K1;
#define TFR(r) { x0 += x1; x1 = tf_rotl(x1, (r)); x1 ^= x0; }
    TFR(13) TFR(15) TFR(26) TFR(6)   x0 += K1; x1 += K2 + 1u;
    TFR(17) TFR(29) TFR(16) TFR(24)  x0 += K2; x1 += K0 + 2u;
    TFR(13) TFR(15) TFR(26) TFR(6)   x0 += K0; x1 += K1 + 3u;
    TFR(17) TFR(29) TFR(16) TFR(24)  x0 += K1; x1 += K2 + 4u;
    TFR(13) TFR(15) TFR(26) TFR(6)   x0 += K2; x1 += K0 + 5u;
#undef TFR
    return x0 ^ x1;
}

// LDS bank-conflict swizzles (see R2 theory): bijective on bank(-pair)s for
// the hot refill pattern p = 8*t' + x0 across lanes t'.
__device__ __forceinline__ int swz2(int p) { return p ^ ((p >> 3) & 15); } // float2 arrays
__device__ __forceinline__ int swz1(int p) { return p ^ ((p >> 3) & 31); } // float arrays

// ---------------------------------------------------------------------------
// Kernel 1: tiny prep — synapse->counter-slot index, FIR kernels, obs kernel
// ---------------------------------------------------------------------------
__global__ void prep_kernel(const float* __restrict__ C_e,
                            const float* __restrict__ C_i,
                            const float* __restrict__ W_syn,
                            const float* __restrict__ W_obs,
                            const float* __restrict__ cosb,   // [13][200]
                            const float* __restrict__ obsb,   // [29][401]
                            int* __restrict__ idx_e, int* __restrict__ idx_i,
                            float* __restrict__ ek, float* __restrict__ ik,
                            float* __restrict__ ok) {
    int i = blockIdx.x * blockDim.x + threadIdx.x;
    if (i < ESYN) {
        int r = 31;                       // slot 31 = dead (subunit 0, dropped)
        for (int g = 1; g < 25; ++g)
            if (C_e[g * ESYN + i] > 0.5f) { r = g - 1; break; }
        idx_e[i] = r;
    } else if (i < ESYN + ISYN) {
        int s = i - ESYN; int r = 31;
        for (int g = 1; g < 25; ++g)
            if (C_i[g * ISYN + s] > 0.5f) { r = g - 1; break; }
        idx_i[s] = r;
    } else if (i < ESYN + ISYN + NGRP * 200) {
        int q = i - (ESYN + ISYN);
        int g = q / 200, j = q % 200;
        float ae = 0.f, ai = 0.f;
        for (int b = 0; b < 13; ++b) {
            float we = W_syn[(g * 13 + b) * 2 + 0];
            float wi = W_syn[(g * 13 + b) * 2 + 1];
            float cb = cosb[b * 200 + j];
            ae = fmaf(we * we, cb, ae);
            ai = fmaf(wi * wi, cb, ai);
        }
        ek[g * 200 + j] = ae;
        ik[g * 200 + j] = -ai;   // i-kernel negated in the reference
    } else if (i < ESYN + ISYN + NGRP * 200 + NGRP * 401) {
        int q = i - (ESYN + ISYN + NGRP * 200);
        int g = q / 401, tau = q % 401;
        float a = 0.f;
        for (int b = 0; b < 29; ++b)
            a = fmaf(W_obs[g * 29 + b], obsb[b * 401 + tau], a);
        ok[g * 401 + tau] = a;
    }
}

// ---------------------------------------------------------------------------
// Kernel 2: spike histogram — synEI [G][T] float2   (memory-bound, ~1 GB read)
// One wave per timestep; prefetch full row before branchy processing.
// ---------------------------------------------------------------------------
__global__ __launch_bounds__(256) void hist_kernel(
        const float* __restrict__ S_e, const float* __restrict__ S_i,
        const int* __restrict__ idx_e, const int* __restrict__ idx_i,
        float2* __restrict__ synEI) {
    __shared__ float cntE[4][32];
    __shared__ float cntI[4][32];
    const int wv = threadIdx.x >> 6;
    const int lane = threadIdx.x & 63;
    const int t = blockIdx.x * 4 + wv;          // grid = 25000 blocks exactly
    if (lane < 32) { cntE[wv][lane] = 0.f; cntI[wv][lane] = 0.f; }
    __syncthreads();

    const float4* re = (const float4*)(S_e + (size_t)t * ESYN);
    const float4* ri = (const float4*)(S_i + (size_t)t * ISYN);
    float4 ve[8], vi[2];
#pragma unroll
    for (int k = 0; k < 8; ++k) {
        int c = lane + 64 * k;
        ve[k] = (c < ESYN / 4) ? re[c] : make_float4(0.f, 0.f, 0.f, 0.f);
    }
#pragma unroll
    for (int k = 0; k < 2; ++k) {
        int c = lane + 64 * k;
        vi[k] = (c < ISYN / 4) ? ri[c] : make_float4(0.f, 0.f, 0.f, 0.f);
    }
#pragma unroll
    for (int k = 0; k < 8; ++k) {
        const int cb = (lane + 64 * k) * 4;
        float4 v = ve[k];
        if (v.x != 0.f) atomicAdd(&cntE[wv][idx_e[cb + 0]], v.x);
        if (v.y != 0.f) atomicAdd(&cntE[wv][idx_e[cb + 1]], v.y);
        if (v.z != 0.f) atomicAdd(&cntE[wv][idx_e[cb + 2]], v.z);
        if (v.w != 0.f) atomicAdd(&cntE[wv][idx_e[cb + 3]], v.w);
    }
#pragma unroll
    for (int k = 0; k < 2; ++k) {
        const int cb = (lane + 64 * k) * 4;
        float4 v = vi[k];
        if (v.x != 0.f) atomicAdd(&cntI[wv][idx_i[cb + 0]], v.x);
        if (v.y != 0.f) atomicAdd(&cntI[wv][idx_i[cb + 1]], v.y);
        if (v.z != 0.f) atomicAdd(&cntI[wv][idx_i[cb + 2]], v.z);
        if (v.w != 0.f) atomicAdd(&cntI[wv][idx_i[cb + 3]], v.w);
    }
    __syncthreads();
    if (lane < NGRP)
        synEI[(size_t)lane * T_DATA + t] = make_float2(cntE[wv][lane], cntI[wv][lane]);
}

// ---------------------------------------------------------------------------
// Kernel 3: FIR filters + sigmoid + threefry bernoulli.
// Block = 128 threads, one subunit g, TT=1024 timesteps; 8 outputs/thread via
// a circular register window; LDS XOR-swizzled to kill bank conflicts.
// ---------------------------------------------------------------------------
constexpr int TT = 1024;
constexpr int BLK3 = 128;
constexpr int SYN_L = 1232;   // roundup16(TT+200)
constexpr int Z_L   = 1440;   // roundup32(TT+400)

__global__ __launch_bounds__(128) void filter_kernel(
        const float* __restrict__ Z,
        const float2* __restrict__ synEI,
        const float* __restrict__ ek, const float* __restrict__ ik,
        const float* __restrict__ ok, const float* __restrict__ Theta,
        float* __restrict__ out) {
    __shared__ float2 syn_l[SYN_L];      // swizzled (e,i) -> ds_read_b64
    __shared__ float  z_l[Z_L];          // swizzled
    __shared__ float2 kern_l[200];       // (ek, ik), broadcast reads
    __shared__ float  ok_l[401];         // broadcast reads

    const int g  = blockIdx.y;
    const int t0 = blockIdx.x * TT;
    const int tid = threadIdx.x;

    const float2* s2 = synEI + (size_t)g * T_DATA;
    for (int p = tid; p < TT + 200; p += BLK3) {
        int t = t0 - 200 + p;
        float2 v = (t >= 0 && t < T_DATA) ? s2[t] : make_float2(0.f, 0.f);
        syn_l[swz2(p)] = v;
    }
    for (int p = tid; p < TT + 400; p += BLK3) {
        int t = t0 - 200 + p;
        z_l[swz1(p)] = (t >= 0 && t < T_DATA) ? Z[t] : 0.f;
    }
    for (int p = tid; p < 200; p += BLK3)
        kern_l[p] = make_float2(ek[g * 200 + p], ik[g * 200 + p]);
    for (int p = tid; p < 401; p += BLK3)
        ok_l[p] = ok[g * 401 + p];
    __syncthreads();

    float accS[8], accZ[8];
#pragma unroll
    for (int k = 0; k < 8; ++k) { accS[k] = 0.f; accZ[k] = 0.f; }

    // --- synaptic FIR: out[t] += sum_j syn[t-1-j]*kern[j], j in [0,200) ---
    {
        const int B = tid * 8 + 199;   // logical index for (k=0, j=0)
        float2 w[8];                   // slot s = (logical - B) & 7
#pragma unroll
        for (int p = 0; p < 8; ++p) w[p] = syn_l[swz2(B + p)];
        for (int nb = 0; nb < 200; nb += 8) {
#pragma unroll
            for (int jj = 0; jj < 8; ++jj) {
                const int n = nb + jj;
                const float2 kv = kern_l[n];
#pragma unroll
                for (int k = 0; k < 8; ++k) {
                    const float2 d = w[(k - jj) & 7];
                    accS[k] = fmaf(d.x, kv.x, fmaf(d.y, kv.y, accS[k]));
                }
                if (n < 199) w[(7 - jj) & 7] = syn_l[swz2(B - n - 1)];
            }
        }
    }

    // --- obs FIR: out[t] += sum_n Z[t+200-n]*ok[n], n in [0,400] ---
    {
        const int Bz = tid * 8 + 400;
        float wz[8];
#pragma unroll
        for (int p = 0; p < 8; ++p) wz[p] = z_l[swz1(Bz + p)];
        for (int nb = 0; nb < 400; nb += 8) {
#pragma unroll
            for (int jj = 0; jj < 8; ++jj) {
                const int n = nb + jj;
                const float kv = ok_l[n];
#pragma unroll
                for (int k = 0; k < 8; ++k)
                    accZ[k] = fmaf(wz[(k - jj) & 7], kv, accZ[k]);
                wz[(7 - jj) & 7] = z_l[swz1(Bz - n - 1)];   // min = tid*8 >= 0
            }
        }
        const float kv = ok_l[400];    // epilogue tap; 400 % 8 == 0 -> slot k
#pragma unroll
        for (int k = 0; k < 8; ++k)
            accZ[k] = fmaf(wz[k], kv, accZ[k]);
    }

    const float theta_g = Theta[g];
#pragma unroll
    for (int k = 0; k < 8; ++k) {
        int t = t0 + tid * 8 + k;
        if (t < T_DATA) {
            double x  = (double)accS[k] + (double)accZ[k] + (double)theta_g;
            double Pd = 1.0 / (1.0 + exp(-x));
            float  Pf = (float)Pd;
            unsigned i = (unsigned)(t * NGRP + g);
            unsigned bits = rng_bits(i);
            float u = __uint_as_float((bits >> 9) | 0x3f800000u) - 1.0f;
            size_t o = (size_t)t * NGRP + g;
            out[o]        = (u < Pf) ? 1.0f : 0.0f;  // Z_out
            out[NTOT + o] = Pf;                      // P
        }
    }
}

extern "C" void kernel_launch(void* const* d_in, const int* in_sizes, int n_in,
                              void* d_out, int out_size, void* d_ws, size_t ws_size,
                              hipStream_t stream) {
    const float* Z     = (const float*)d_in[0];
    const float* S_e   = (const float*)d_in[1];
    const float* S_i   = (const float*)d_in[2];
    const float* C_e   = (const float*)d_in[3];
    const float* C_i   = (const float*)d_in[4];
    const float* W_syn = (const float*)d_in[5];
    const float* Theta = (const float*)d_in[6];
    const float* W_obs = (const float*)d_in[7];
    const float* cosb  = (const float*)d_in[8];
    const float* obsb  = (const float*)d_in[9];

    float* ws    = (float*)d_ws;
    float2* synEI = (float2*)ws;             // 2,400,000 float2
    float* ek    = ws + 2 * NTOT;            // 24*200
    float* ik    = ek + NGRP * 200;          // 24*200
    float* ok    = ik + NGRP * 200;          // 24*401
    int*   idx_e = (int*)(ok + NGRP * 401);  // 2000
    int*   idx_i = idx_e + ESYN;             // 500
    // total ~19.3 MiB of d_ws

    const int prep_items = ESYN + ISYN + NGRP * 200 + NGRP * 401;
    prep_kernel<<<(prep_items + 255) / 256, 256, 0, stream>>>(
        C_e, C_i, W_syn, W_obs, cosb, obsb, idx_e, idx_i, ek, ik, ok);

    hist_kernel<<<T_DATA / 4, 256, 0, stream>>>(S_e, S_i, idx_e, idx_i, synEI);

    dim3 grid3((T_DATA + TT - 1) / TT, NGRP);
    filter_kernel<<<grid3, BLK3, 0, stream>>>(Z, synEI, ek, ik, ok, Theta,
                                              (float*)d_out);
}